// Round 8
// baseline (309.980 us; speedup 1.0000x reference)
//
#include <hip/hip_runtime.h>

#define BB 8
#define NC 12
#define NC1 11
#define HH 512
#define WW 512
#define GH 8        // h rows per thread
#define WT 8        // w per block

static constexpr size_t CH = (size_t)HH * WW;   // 262144

// output offsets (flat floats, in return order)
static constexpr size_t OFF_LSM   = 0;
static constexpr size_t OFF_CLP   = 23068672;
static constexpr size_t OFF_CLEAN = 23113728;
static constexpr size_t OFF_STD   = 48279552;
static constexpr size_t OFF_TOPO  = 48324608;
static constexpr size_t OFF_CONT  = 48365568;
static constexpr size_t OFF_CURV  = 48410536;

// ws: lp only, [88][512] floats = 180 KB
__device__ __forceinline__ unsigned f2bf(float f) {   // RNE float->bf16 bits
    unsigned u = __float_as_uint(f);
    return (u + 0x7fffu + ((u >> 16) & 1u)) >> 16;
}

// ---------------------------------------------------------------- fused: stats + lsm + clean (block-local column)
// grid 512 blocks x 512 thr; thread = (ck 0..63, wl 0..7); block = (b, 8-w strip)
__global__ __launch_bounds__(512, 4) void fused_main(const float* __restrict__ in,
                                                     float* __restrict__ lp_ws,
                                                     float* __restrict__ out) {
    const int tid = threadIdx.x;
    const int wl = tid & 7;          // fast: w lane
    const int ck = tid >> 3;         // 0..63, 8-h chunk
    const int lane = tid & 63;
    const int g = tid >> 6;          // wave id 0..7

    // XCD pair-swizzle: logical lin = b*64 + wt; pairs (wt even/odd) share bid%8
    const int bid = blockIdx.x;
    const int p = ((bid >> 4) << 3) | (bid & 7);
    const int e = (bid >> 3) & 1;
    const int lin = p * 2 + e;
    const int b = lin >> 6, wt = lin & 63;
    const int w = wt * WT + wl;

    __shared__ float sE[8][8], sP[8][8], sQ[8][8];

    unsigned xpk[NC1][GH / 2];       // packed bf16 x (44 VGPRs)
    float base[NC1], invr[NC1];

    float xn[GH];
    {   // preload class 0
        const float* pin = in + ((size_t)(b * NC) * HH + ck * GH) * WW + w;
#pragma unroll
        for (int i = 0; i < GH; ++i) xn[i] = pin[(size_t)i * WW];
    }

#pragma unroll
    for (int c = 0; c < NC1; ++c) {
        float xc[GH];
#pragma unroll
        for (int i = 0; i < GH; ++i) xc[i] = xn[i];
        if (c < NC1 - 1) {           // prefetch next class
            const float* pin = in + ((size_t)(b * NC + c + 1) * HH + ck * GH) * WW + w;
#pragma unroll
            for (int i = 0; i < GH; ++i) xn[i] = pin[(size_t)i * WW];
        }
        float E = 0.f, P = 0.f, Q = 0.f;
#pragma unroll
        for (int i = 0; i < GH; ++i) {
            const float ev = expf(xc[i]);
            const float h = (float)(ck * GH + i);
            E += ev; P += h * ev; Q += h * h * ev;
        }
#pragma unroll
        for (int j = 0; j < GH / 2; ++j)
            xpk[c][j] = f2bf(xc[2 * j]) | (f2bf(xc[2 * j + 1]) << 16);

        // in-wave: inclusive prefix of E over 8 ck (lane stride 8); all-total for E,P,Q
        float Einc = E;
#pragma unroll
        for (int s = 8; s <= 32; s <<= 1) {
            const float u = __shfl_up(Einc, (unsigned)s);
            Einc += (lane >= s) ? u : 0.f;
        }
        float Et = E, Pt = P, Qt = Q;
#pragma unroll
        for (int s = 8; s <= 32; s <<= 1) {
            Et += __shfl_xor(Et, s);
            Pt += __shfl_xor(Pt, s);
            Qt += __shfl_xor(Qt, s);
        }
        if (lane < 8) { sE[g][wl] = Et; sP[g][wl] = Pt; sQ[g][wl] = Qt; }
        __syncthreads();

        float S = 0.f, Pq = 0.f, Qq = 0.f, gpre = 0.f;
#pragma unroll
        for (int g2 = 0; g2 < 8; ++g2) {
            const float eg = sE[g2][wl];
            if (g2 < g) gpre += eg;
            S += eg; Pq += sP[g2][wl]; Qq += sQ[g2][wl];
        }
        const float inv = 1.f / S;
        base[c] = (gpre + (Einc - E)) * inv;   // exclusive normalized prefix before this chunk
        invr[c] = inv;
        if (ck == 0) {
            const float lpv = Pq * inv;
            float var = Qq * inv - lpv * lpv; if (var < 0.f) var = 0.f;
            const size_t o = (size_t)(b * NC1 + c) * WW + w;
            out[OFF_STD + o] = sqrtf(var);
            lp_ws[o] = lpv;
        }
        __syncthreads();                        // LDS reuse next class
    }

    // ---------------- phase 3: lsm + clean_masks from registers (zero reads)
    float lg[NC1], cum[NC1];
#pragma unroll
    for (int c = 0; c < NC1; ++c) { lg[c] = -logf(invr[c]); cum[c] = base[c]; }

    const size_t hb = (size_t)(ck * GH) * WW + w;
    float* lsm = out + OFF_LSM + (size_t)b * NC1 * CH + hb;
    float* cln = out + OFF_CLEAN + (size_t)b * NC * CH + hb;
#pragma unroll
    for (int i = 0; i < GH; ++i) {
        const size_t ho = (size_t)i * WW;
#pragma unroll
        for (int c = 0; c < NC1; ++c) {
            const unsigned pk = xpk[c][i >> 1];
            const float xv = __uint_as_float((i & 1) ? (pk & 0xffff0000u) : (pk << 16));
            lsm[(size_t)c * CH + ho] = xv - lg[c];
            cum[c] += expf(xv) * invr[c];
        }
        float tc = cum[0];
        cln[ho] = 1.f - tc;
#pragma unroll
        for (int k = 1; k < NC1; ++k) {
            const float t2 = fmaxf(cum[k] + tc - 1.f, 0.f);
            cln[(size_t)k * CH + ho] = tc - t2;
            tc = t2;
        }
        cln[(size_t)NC1 * CH + ho] = tc;
    }
}

// ---------------------------------------------------------------- smalls from lp (proven round-1 k3)
__global__ __launch_bounds__(512) void k_small(const float* __restrict__ lp,
                                               float* __restrict__ out) {
    const int w = threadIdx.x;
    const int b = blockIdx.x;
    const float CM[NC1] = {1.2261f, 1.1558f, 1.1161f, 1.1195f, 2.7202f, 2.3714f,
                           1.7055f, 3.2717f, 2.6716f, 5.0418f, 0.4293f};
    const int wm = (w - 5 < 0) ? 0 : w - 5;
    const int wp = (w + 5 > WW - 1) ? WW - 1 : w + 5;
    float m = 0.f, prev = 0.f;
    for (int c = 0; c < NC1; ++c) {
        const size_t rb = (size_t)(b * NC1 + c) * WW;
        const float lv = lp[rb + w];
        m = (c == 0) ? lv : fmaxf(m, lv);
        out[OFF_CLP + rb + w] = m;
        if (c > 0)
            out[OFF_TOPO + (size_t)(b * (NC1 - 1) + (c - 1)) * WW + w] = fmaxf(prev - lv, 0.f);
        prev = lv;
        if (w < WW - 1) {
            const float nxt = lp[rb + w + 1];
            out[OFF_CONT + (size_t)(b * NC1 + c) * (WW - 1) + w] = fabsf(lv - nxt);
        }
        const float a  = lp[rb + wm];
        const float bb = lp[rb + wp];
        const float fo = bb - a;
        const float so = a - 2.f * lv + bb;
        const float bs = 1.f + fo * fo;
        out[OFF_CURV + rb + w] = fabsf(so / (bs * sqrtf(bs))) - CM[c];
    }
}

extern "C" void kernel_launch(void* const* d_in, const int* in_sizes, int n_in,
                              void* d_out, int out_size, void* d_ws, size_t ws_size,
                              hipStream_t stream) {
    const float* in = (const float*)d_in[0];
    float* out = (float*)d_out;
    float* lp_ws = (float*)d_ws;   // 180 KB

    hipLaunchKernelGGL(fused_main, dim3(512), dim3(512), 0, stream, in, lp_ws, out);
    hipLaunchKernelGGL(k_small, dim3(BB), dim3(512), 0, stream, lp_ws, out);
}

// Round 9
// 274.657 us; speedup vs baseline: 1.1286x; 1.1286x over previous
//
#include <hip/hip_runtime.h>
#include <hip/hip_cooperative_groups.h>

namespace cg = cooperative_groups;

#define BB 8
#define NC 12
#define NC1 11
#define HH 512
#define WW 512
#define NCH 32     // 16-h chunks per column
#define HC 16
#define NBC (BB*NC1) // 88

static constexpr size_t CH = (size_t)HH * WW;   // 262144

// output offsets (flat floats, in return order)
static constexpr size_t OFF_LSM   = 0;
static constexpr size_t OFF_CLP   = 23068672;
static constexpr size_t OFF_CLEAN = 23113728;
static constexpr size_t OFF_STD   = 48279552;
static constexpr size_t OFF_TOPO  = 48324608;
static constexpr size_t OFF_CONT  = 48365568;
static constexpr size_t OFF_CURV  = 48410536;

// workspace layout (floats) — identical to proven rounds 1-6 footprint (17.8 MB)
static constexpr size_t NE    = (size_t)NBC * NCH * WW;    // 1441792
static constexpr size_t WS_E  = 0;                         // -> normalized cum bases in place
static constexpr size_t WS_P  = NE;
static constexpr size_t WS_Q  = 2 * NE;
static constexpr size_t WS_INV = 3 * NE;                   // [88][512]
static constexpr size_t NST   = (size_t)NBC * WW;          // 45056
static constexpr size_t WS_LOG = WS_INV + NST;
static constexpr size_t WS_LP  = WS_LOG + NST;

__device__ __forceinline__ unsigned f2bf(float f) {   // RNE float->bf16 bits
    unsigned u = __float_as_uint(f);
    return (u + 0x7fffu + ((u >> 16) & 1u)) >> 16;
}

__device__ __forceinline__ void smalls_body(const float* __restrict__ lp,
                                            float* __restrict__ out, int b, int w) {
    const float CM[NC1] = {1.2261f, 1.1558f, 1.1161f, 1.1195f, 2.7202f, 2.3714f,
                           1.7055f, 3.2717f, 2.6716f, 5.0418f, 0.4293f};
    const int wm = (w - 5 < 0) ? 0 : w - 5;
    const int wp = (w + 5 > WW - 1) ? WW - 1 : w + 5;
    float m = 0.f, prev = 0.f;
    for (int c = 0; c < NC1; ++c) {
        const size_t rb = (size_t)(b * NC1 + c) * WW;
        const float lv = lp[rb + w];
        m = (c == 0) ? lv : fmaxf(m, lv);
        out[OFF_CLP + rb + w] = m;
        if (c > 0)
            out[OFF_TOPO + (size_t)(b * (NC1 - 1) + (c - 1)) * WW + w] = fmaxf(prev - lv, 0.f);
        prev = lv;
        if (w < WW - 1) {
            const float nxt = lp[rb + w + 1];
            out[OFF_CONT + (size_t)(b * NC1 + c) * (WW - 1) + w] = fabsf(lv - nxt);
        }
        const float a  = lp[rb + wm];
        const float bb = lp[rb + wp];
        const float fo = bb - a;
        const float so = a - 2.f * lv + bb;
        const float bs = 1.f + fo * fo;
        out[OFF_CURV + rb + w] = fabsf(so / (bs * sqrtf(bs))) - CM[c];
    }
}

// ================================================================ cooperative fused kernel
// grid 256 blocks x 512 thr; block=(b, ck), thread=w  -> all accesses 2KB-row coalesced
__global__ __launch_bounds__(512) void fused_coop(const float* __restrict__ in,
                                                  float* __restrict__ ws,
                                                  float* __restrict__ out) {
    cg::grid_group grid = cg::this_grid();
    const int t = threadIdx.x;            // w
    const int bid = blockIdx.x;           // 0..255
    const int b = bid >> 5, ck = bid & 31;
    const int w = t;

    unsigned xpk[NC1][HC / 2];            // packed bf16 x: 88 VGPRs

    // ---------------- phase 1: stream input once; E/P/Q per 16-h chunk
#pragma unroll
    for (int c = 0; c < NC1; ++c) {
        const float* p = in + ((size_t)(b * NC + c) * HH + ck * HC) * WW + w;
        float E = 0.f, P = 0.f, Q = 0.f;
#pragma unroll
        for (int i = 0; i < HC; ++i) {
            const float xv = p[(size_t)i * WW];
            const float e = expf(xv);
            const float h = (float)(ck * HC + i);
            E += e; P += h * e; Q += h * h * e;
            if (i & 1) xpk[c][i >> 1] |= f2bf(xv) << 16;
            else       xpk[c][i >> 1]  = f2bf(xv);
        }
        const size_t o = ((size_t)(b * NC1 + c) * NCH + ck) * WW + w;
        ws[WS_E + o] = E; ws[WS_P + o] = P; ws[WS_Q + o] = Q;
    }
    __threadfence();
    grid.sync();

    // ---------------- phase 2: column reduce, 2 lanes per column
    {
        const int lin = bid * 512 + t;
        const int col = lin >> 1, q = lin & 1;
        if (col < (int)NST) {
            const int bc = col >> 9, w2 = col & 511;
            const size_t cb = (size_t)bc * NCH * WW + w2;
            float e[16];
            float Se = 0.f, Sp = 0.f, Sq = 0.f;
#pragma unroll
            for (int k = 0; k < 16; ++k) {
                const size_t oo = cb + (size_t)(q * 16 + k) * WW;
                e[k] = ws[WS_E + oo];
                Se += e[k];
                Sp += ws[WS_P + oo];
                Sq += ws[WS_Q + oo];
            }
            const float So = __shfl_xor(Se, 1);
            const float Po = __shfl_xor(Sp, 1);
            const float Qo = __shfl_xor(Sq, 1);
            const float S = Se + So, P = Sp + Po, Q = Sq + Qo;
            const float inv = 1.f / S;
            float run = (q == 1) ? So : 0.f;
#pragma unroll
            for (int k = 0; k < 16; ++k) {  // normalized cum base BEFORE each chunk (in place)
                const size_t oo = cb + (size_t)(q * 16 + k) * WW;
                ws[WS_E + oo] = run * inv;
                run += e[k];
            }
            if (q == 0) {
                const float lp = P * inv;
                float var = Q * inv - lp * lp; if (var < 0.f) var = 0.f;
                const size_t so = (size_t)bc * WW + w2;
                ws[WS_INV + so] = inv;
                ws[WS_LOG + so] = logf(S);
                ws[WS_LP + so]  = lp;
                out[OFF_STD + so] = sqrtf(var);
            }
        }
    }
    __threadfence();
    grid.sync();

    // ---------------- phase 3: lsm + clean_masks from register-resident x
    {
        float cum[NC1], iv[NC1], lg[NC1];
#pragma unroll
        for (int c = 0; c < NC1; ++c) {
            const size_t bc = (size_t)(b * NC1 + c);
            cum[c] = ws[WS_E + (bc * NCH + ck) * WW + w];
            iv[c]  = ws[WS_INV + bc * WW + w];
            lg[c]  = ws[WS_LOG + bc * WW + w];
        }
        const size_t hb = (size_t)(ck * HC) * WW + w;
        float* lsm = out + OFF_LSM + (size_t)b * NC1 * CH + hb;
        float* cln = out + OFF_CLEAN + (size_t)b * NC * CH + hb;
#pragma unroll
        for (int i = 0; i < HC; ++i) {
            const size_t ho = (size_t)i * WW;
#pragma unroll
            for (int c = 0; c < NC1; ++c) {
                const unsigned pk = xpk[c][i >> 1];
                const float xv = __uint_as_float((i & 1) ? (pk & 0xffff0000u) : (pk << 16));
                lsm[(size_t)c * CH + ho] = xv - lg[c];
                cum[c] += expf(xv) * iv[c];
            }
            float tc = cum[0];
            cln[ho] = 1.f - tc;
#pragma unroll
            for (int k = 1; k < NC1; ++k) {
                const float t2 = fmaxf(cum[k] + tc - 1.f, 0.f);
                cln[(size_t)k * CH + ho] = tc - t2;
                tc = t2;
            }
            cln[(size_t)NC1 * CH + ho] = tc;
        }
    }

    if (ck == 0) smalls_body(ws + WS_LP, out, b, w);
}

// ================================================================ fallback pipeline (proven round-6, 78 µs)
__global__ __launch_bounds__(512) void k1_partials(const float* __restrict__ in,
                                                   float* __restrict__ ws) {
    const int w4 = threadIdx.x & 127;
    const int cg2 = threadIdx.x >> 7;
    const int chunk = blockIdx.x * 4 + cg2;
    const int bc = blockIdx.y;
    const int b = bc / NC1, c = bc % NC1;

    const float* p = in + ((size_t)(b * NC + c) * HH + (size_t)chunk * HC) * WW + 4 * w4;
    float4 E = make_float4(0.f, 0.f, 0.f, 0.f);
    float4 P = E, Q = E;
#pragma unroll
    for (int i = 0; i < HC; ++i) {
        const float4 x = *(const float4*)(p + (size_t)i * WW);
        const float h = (float)(chunk * HC + i);
        const float ex = expf(x.x), ey = expf(x.y), ez = expf(x.z), ew = expf(x.w);
        E.x += ex; E.y += ey; E.z += ez; E.w += ew;
        P.x += h * ex; P.y += h * ey; P.z += h * ez; P.w += h * ew;
        Q.x += h * h * ex; Q.y += h * h * ey; Q.z += h * h * ez; Q.w += h * h * ew;
    }
    const size_t o = ((size_t)bc * NCH + chunk) * WW + 4 * w4;
    *(float4*)(ws + WS_E + o) = E;
    *(float4*)(ws + WS_P + o) = P;
    *(float4*)(ws + WS_Q + o) = Q;
}

__global__ __launch_bounds__(512) void k2_reduce(float* __restrict__ ws,
                                                 float* __restrict__ out) {
    const int w = threadIdx.x & 127;
    const int q = threadIdx.x >> 7;
    const int wt = blockIdx.x;
    const int bc = blockIdx.y;
    const int wg = wt * 128 + w;

    __shared__ float sE[4][128], sP[4][128], sQ[4][128];

    const size_t base = (size_t)bc * NCH * WW + wg;
    float e[8];
    float Es = 0.f, Ps = 0.f, Qs = 0.f;
#pragma unroll
    for (int k = 0; k < 8; ++k) {
        const int ch = q * 8 + k;
        e[k] = ws[WS_E + base + (size_t)ch * WW];
        Es += e[k];
        Ps += ws[WS_P + base + (size_t)ch * WW];
        Qs += ws[WS_Q + base + (size_t)ch * WW];
    }
    sE[q][w] = Es; sP[q][w] = Ps; sQ[q][w] = Qs;
    __syncthreads();

    const float S = sE[0][w] + sE[1][w] + sE[2][w] + sE[3][w];
    const float inv = 1.f / S;
    float pre = 0.f;
    for (int q2 = 0; q2 < q; ++q2) pre += sE[q2][w];
#pragma unroll
    for (int k = 0; k < 8; ++k) {
        const int ch = q * 8 + k;
        ws[WS_E + base + (size_t)ch * WW] = pre * inv;
        pre += e[k];
    }
    if (q == 0) {
        const float P = sP[0][w] + sP[1][w] + sP[2][w] + sP[3][w];
        const float Q = sQ[0][w] + sQ[1][w] + sQ[2][w] + sQ[3][w];
        const float lp = P * inv;
        float var = Q * inv - lp * lp;
        if (var < 0.f) var = 0.f;
        const size_t o = (size_t)bc * WW + wg;
        ws[WS_INV + o] = inv;
        ws[WS_LOG + o] = logf(S);
        ws[WS_LP + o]  = lp;
        out[OFF_STD + o] = sqrtf(var);
    }
}

__global__ __launch_bounds__(256) void k4_main(const float* __restrict__ in,
                                               const float* __restrict__ ws,
                                               float* __restrict__ out) {
    const int t = threadIdx.x;
    const int wh = blockIdx.x, chunk = blockIdx.y, b = blockIdx.z;
    const int w = wh * 256 + t;

    float cum[NC1], inv[NC1], lgs[NC1];
#pragma unroll
    for (int c = 0; c < NC1; ++c) {
        const size_t bc = (size_t)(b * NC1 + c);
        cum[c] = ws[WS_E + (bc * NCH + chunk) * WW + w];
        inv[c] = ws[WS_INV + bc * WW + w];
        lgs[c] = ws[WS_LOG + bc * WW + w];
    }

    const float* ip = in + (size_t)b * NC * CH + (size_t)(chunk * HC) * WW + w;
    float* lsm = out + OFF_LSM + (size_t)b * NC1 * CH + (size_t)(chunk * HC) * WW + w;
    float* cln = out + OFF_CLEAN + (size_t)b * NC * CH + (size_t)(chunk * HC) * WW + w;

    for (int i = 0; i < HC; ++i) {
        const size_t ho = (size_t)i * WW;
        float x[NC1];
#pragma unroll
        for (int c = 0; c < NC1; ++c)
            x[c] = ip[(size_t)c * CH + ho];
#pragma unroll
        for (int c = 0; c < NC1; ++c) {
            cum[c] += expf(x[c]) * inv[c];
            lsm[(size_t)c * CH + ho] = x[c] - lgs[c];
        }
        float tc = cum[0];
        cln[ho] = 1.f - tc;
#pragma unroll
        for (int k = 1; k < NC1; ++k) {
            const float t2 = fmaxf(cum[k] + tc - 1.f, 0.f);
            cln[(size_t)k * CH + ho] = tc - t2;
            tc = t2;
        }
        cln[(size_t)NC1 * CH + ho] = tc;
    }

    if (chunk != 0) return;
    smalls_body(ws + WS_LP, out, b, w);
}

extern "C" void kernel_launch(void* const* d_in, const int* in_sizes, int n_in,
                              void* d_out, int out_size, void* d_ws, size_t ws_size,
                              hipStream_t stream) {
    const float* in = (const float*)d_in[0];
    float* out = (float*)d_out;
    float* ws = (float*)d_ws;

    void* args[] = { (void*)&in, (void*)&ws, (void*)&out };
    hipError_t err = hipLaunchCooperativeKernel(reinterpret_cast<void*>(fused_coop),
                                                dim3(256), dim3(512), args, 0, stream);
    if (err != hipSuccess) {
        // fallback: proven 3-kernel pipeline
        hipLaunchKernelGGL(k1_partials, dim3(NCH / 4, NBC), dim3(512), 0, stream, in, ws);
        hipLaunchKernelGGL(k2_reduce, dim3(4, NBC), dim3(512), 0, stream, ws, out);
        hipLaunchKernelGGL(k4_main, dim3(2, NCH, BB), dim3(256), 0, stream, in, ws, out);
    }
}